// Round 4
// baseline (181.670 us; speedup 1.0000x reference)
//
#include <hip/hip_runtime.h>
#include <math.h>

#define CC 64
#define HH 80
#define WW 160
#define BB 3
#define LL 4
#define HW (HH * WW)          // 12800
#define EPSf 1e-5f
#define NEGf -1e30f

typedef __attribute__((ext_vector_type(8))) short bf16x8;
typedef __attribute__((ext_vector_type(4))) float f32x4;

union BU { unsigned short s[8]; bf16x8 v; };

__device__ __forceinline__ unsigned short f2bf(float f) {
    unsigned int u = __float_as_uint(f);
    u = u + 0x7fffu + ((u >> 16) & 1u);      // RNE
    return (unsigned short)(u >> 16);
}
__device__ __forceinline__ float b2f(unsigned short h) {
    return __uint_as_float(((unsigned int)h) << 16);
}

__device__ __forceinline__ void src_xy(const float* __restrict__ th, int pix,
                                       float& px, float& py) {
    int w = pix % WW, h = pix / WW;
    float gx = -1.f + 2.f * (float)w / (float)(WW - 1);
    float gy = -1.f + 2.f * (float)h / (float)(HH - 1);
    float sx = th[0] * gx + th[1] * gy + th[2];
    float sy = th[3] * gx + th[4] * gy + th[5];
    px = (sx + 1.f) * (float)(WW - 1) * 0.5f;
    py = (sy + 1.f) * (float)(HH - 1) * 0.5f;
}

struct Tap { int a00, a01, a10, a11; float w00, w01, w10, w11; };

__device__ __forceinline__ Tap mk_tap(float px, float py) {
    Tap tp;
    float x0f = floorf(px), y0f = floorf(py);
    float wx = px - x0f, wy = py - y0f;
    int x0 = (int)x0f, y0 = (int)y0f, x1 = x0 + 1, y1 = y0 + 1;
    float bx0 = (x0 >= 0 && x0 < WW) ? 1.f : 0.f;
    float bx1 = (x1 >= 0 && x1 < WW) ? 1.f : 0.f;
    float by0 = (y0 >= 0 && y0 < HH) ? 1.f : 0.f;
    float by1 = (y1 >= 0 && y1 < HH) ? 1.f : 0.f;
    int xc0 = min(max(x0, 0), WW - 1), xc1 = min(max(x1, 0), WW - 1);
    int yc0 = min(max(y0, 0), HH - 1), yc1 = min(max(y1, 0), HH - 1);
    tp.w00 = (1.f - wx) * (1.f - wy) * bx0 * by0;
    tp.w01 = wx * (1.f - wy) * bx1 * by0;
    tp.w10 = (1.f - wx) * wy * bx0 * by1;
    tp.w11 = wx * wy * bx1 * by1;
    tp.a00 = yc0 * WW + xc0; tp.a01 = yc0 * WW + xc1;
    tp.a10 = yc1 * WW + xc0; tp.a11 = yc1 * WW + xc1;
    return tp;
}

// ---------------- prep: weight transpose+bf16, BN folding ----------------

__global__ __launch_bounds__(256) void k_prep(
    const float* __restrict__ w1, const float* __restrict__ w2,
    const float* __restrict__ mlpw,
    const float* __restrict__ cb1, const float* __restrict__ g1,
    const float* __restrict__ be1, const float* __restrict__ rm1, const float* __restrict__ rv1,
    const float* __restrict__ cb2, const float* __restrict__ g2,
    const float* __restrict__ be2, const float* __restrict__ rm2, const float* __restrict__ rv2,
    const float* __restrict__ cb3, const float* __restrict__ g3,
    const float* __restrict__ be3, const float* __restrict__ rm3, const float* __restrict__ rv3,
    unsigned short* __restrict__ w1T, unsigned short* __restrict__ w2T,
    unsigned short* __restrict__ mwT,
    float* __restrict__ kk1, float* __restrict__ bb1,
    float* __restrict__ kk2, float* __restrict__ bb2,
    float* __restrict__ kk3, float* __restrict__ bb3)
{
    int idx = blockIdx.x * 256 + threadIdx.x;
    if (idx < 16384) {                       // w1T[o][c] = w1[c][o]
        int o = idx >> 7, c = idx & 127;
        w1T[idx] = f2bf(w1[c * 128 + o]);
    } else if (idx < 20480) {                // w2T[o2][o] = w2[o][o2]
        int i = idx - 16384;
        int o2 = i >> 7, o = i & 127;
        w2T[i] = f2bf(w2[o * 32 + o2]);
    } else if (idx < 24576) {                // mwT[d][c] = mlpw[c][d]
        int i = idx - 20480;
        int d = i >> 6, c = i & 63;
        mwT[i] = f2bf(mlpw[c * 64 + d]);
    } else if (idx < 24704) {
        int o = idx - 24576;
        float k = g1[o] * rsqrtf(rv1[o] + EPSf);
        kk1[o] = k; bb1[o] = fmaf(cb1[o] - rm1[o], k, be1[o]);
    } else if (idx < 24736) {
        int o = idx - 24704;
        float k = g2[o] * rsqrtf(rv2[o] + EPSf);
        kk2[o] = k; bb2[o] = fmaf(cb2[o] - rm2[o], k, be2[o]);
    } else if (idx < 24744) {
        int o = idx - 24736;
        float k = g3[o] * rsqrtf(rv3[o] + EPSf);
        kk3[o] = k; bb3[o] = fmaf(cb3[o] - rm3[o], k, be3[o]);
    }
}

// ---------------- fused: wave w handles neighbor j=w; 16-pixel tiles ----------------
// grid: 3 b x 800 tiles of 16 pixels; 256 threads = 4 waves.
// lane (q,r16): pixel = pix0 + r16, channels ks*32 + q*8 + i (MFMA A-frag layout)

__global__ __launch_bounds__(256, 5) void k_fused(
    const float* __restrict__ x, const float* __restrict__ mask,
    const int* __restrict__ rec, const float* __restrict__ ptm,
    const unsigned short* __restrict__ w1T, const unsigned short* __restrict__ w2T,
    const unsigned short* __restrict__ mwT,
    const float* __restrict__ kk1, const float* __restrict__ bb1,
    const float* __restrict__ kk2, const float* __restrict__ bb2,
    const float* __restrict__ kk3, const float* __restrict__ bb3,
    const float* __restrict__ w3, const float* __restrict__ w4,
    const float* __restrict__ cb4, const float* __restrict__ mlp_b,
    float* __restrict__ out)
{
    __shared__ __align__(16) char pool[27136];
    unsigned short* nbr_s = (unsigned short*)pool;          // [4 j][16 px][72] bf16
    unsigned short* H1s   = (unsigned short*)(pool + 9216); // per-wave [16 px][136] bf16
    float* s_s   = (float*)(pool + 26624);                  // [4][16]
    float* com_s = (float*)(pool + 26880);                  // [4][16]

    int t = threadIdx.x;
    int b = blockIdx.x / 800, tile = blockIdx.x % 800;
    int pix0 = tile * 16;
    int wave = t >> 6, lane = t & 63, q = lane >> 4, r16 = lane & 15;
    int pix = pix0 + r16;

    int r0 = rec[0], r1 = rec[1], r2 = rec[2];
    int rb = (b == 0) ? r0 : ((b == 1) ? r1 : r2);
    int off = (b >= 1 ? r0 : 0) + (b >= 2 ? r1 : 0);
    bool valid = (wave < rb);

    unsigned short* Hw = H1s + wave * (16 * 136);
    float* H2w = (float*)Hw;   // overlay: written only after all H1 reads (dataflow-ordered)
    const f32x4 z4 = {0.f, 0.f, 0.f, 0.f};

    if (valid) {
        // ---- gather nbr channels for pixel `pix`, j = wave ----
        const float* th = ptm + (size_t)(b * 4 + wave) * 24;   // ptm[b][wave][0]
        float px_, py_; src_xy(th, pix, px_, py_);
        Tap tp = mk_tap(px_, py_);
        const float* feat = x + (size_t)(off + wave) * CC * HW;
        BU u0, u1;
        #pragma unroll
        for (int i = 0; i < 8; ++i) {
            const float* f0 = feat + (size_t)(q * 8 + i) * HW;
            float v0 = tp.w00 * f0[tp.a00] + tp.w01 * f0[tp.a01]
                     + tp.w10 * f0[tp.a10] + tp.w11 * f0[tp.a11];
            u0.s[i] = f2bf(v0);
            const float* f1 = feat + (size_t)(32 + q * 8 + i) * HW;
            float v1 = tp.w00 * f1[tp.a00] + tp.w01 * f1[tp.a01]
                     + tp.w10 * f1[tp.a10] + tp.w11 * f1[tp.a11];
            u1.s[i] = f2bf(v1);
        }
        // warped mask (q==0 lanes, same tap as this lane's pixel)
        float wm = 0.f;
        if (q == 0) {
            const float* mk = mask + (size_t)(b * 4 + wave) * HW;
            wm = tp.w00 * mk[tp.a00] + tp.w01 * mk[tp.a01]
               + tp.w10 * mk[tp.a10] + tp.w11 * mk[tp.a11];
        }
        // publish nbr fragments for fuse stage
        *(bf16x8*)&nbr_s[(wave * 16 + r16) * 72 + q * 8]      = u0.v;
        *(bf16x8*)&nbr_s[(wave * 16 + r16) * 72 + 32 + q * 8] = u1.v;

        // ---- ego fragments ----
        BU v0u, v1u;
        const float* xe = x + (size_t)off * CC * HW + pix;
        #pragma unroll
        for (int i = 0; i < 8; ++i) {
            v0u.s[i] = f2bf(xe[(size_t)(q * 8 + i) * HW]);
            v1u.s[i] = f2bf(xe[(size_t)(32 + q * 8 + i) * HW]);
        }

        // ---- layer 1: [nbr;ego](128) -> 128 ----
        f32x4 acc1[8];
        #pragma unroll
        for (int nt = 0; nt < 8; ++nt) acc1[nt] = z4;
        #pragma unroll
        for (int ks = 0; ks < 4; ++ks) {
            bf16x8 A = (ks == 0) ? u0.v : (ks == 1) ? u1.v : (ks == 2) ? v0u.v : v1u.v;
            int kcol = ks * 32 + q * 8;
            #pragma unroll
            for (int nt = 0; nt < 8; ++nt) {
                bf16x8 bw = *(const bf16x8*)(w1T + (size_t)(nt * 16 + r16) * 128 + kcol);
                acc1[nt] = __builtin_amdgcn_mfma_f32_16x16x32_bf16(A, bw, acc1[nt], 0, 0, 0);
            }
        }
        #pragma unroll
        for (int nt = 0; nt < 8; ++nt) {
            int o = nt * 16 + r16;
            float kv = kk1[o], bv = bb1[o];
            #pragma unroll
            for (int r = 0; r < 4; ++r) {
                float h = fmaxf(fmaf(acc1[nt][r], kv, bv), 0.f);
                Hw[(q * 4 + r) * 136 + o] = f2bf(h);
            }
        }

        // ---- layer 2: 128 -> 32 (A from own wave's H1 rows) ----
        f32x4 acc2[2]; acc2[0] = z4; acc2[1] = z4;
        #pragma unroll
        for (int ks = 0; ks < 4; ++ks) {
            int kcol = ks * 32 + q * 8;
            bf16x8 A = *(const bf16x8*)&Hw[r16 * 136 + kcol];
            #pragma unroll
            for (int nt = 0; nt < 2; ++nt) {
                bf16x8 bw = *(const bf16x8*)(w2T + (size_t)(nt * 16 + r16) * 128 + kcol);
                acc2[nt] = __builtin_amdgcn_mfma_f32_16x16x32_bf16(A, bw, acc2[nt], 0, 0, 0);
            }
        }
        #pragma unroll
        for (int nt = 0; nt < 2; ++nt) {
            int o = nt * 16 + r16;
            float kv = kk2[o], bv = bb2[o];
            #pragma unroll
            for (int r = 0; r < 4; ++r) {
                float h = fmaxf(fmaf(acc2[nt][r], kv, bv), 0.f);
                H2w[(q * 4 + r) * 36 + o] = h;
            }
        }

        // ---- layers 3-4 (q==0 lanes; px = r16; same-wave LDS, no barrier) ----
        if (q == 0) {
            float a3[8];
            #pragma unroll
            for (int o = 0; o < 8; ++o) a3[o] = 0.f;
            #pragma unroll 4
            for (int c = 0; c < 32; ++c) {
                float hv = H2w[r16 * 36 + c];
                #pragma unroll
                for (int o = 0; o < 8; ++o) a3[o] = fmaf(hv, w3[c * 8 + o], a3[o]);
            }
            float s = cb4[0];
            #pragma unroll
            for (int o = 0; o < 8; ++o) {
                float h = fmaxf(fmaf(a3[o], kk3[o], bb3[o]), 0.f);
                s = fmaf(h, w4[o], s);
            }
            s = fmaxf(s, 0.f);
            s_s[wave * 16 + r16]   = (wm == 0.f) ? NEGf : s;
            com_s[wave * 16 + r16] = wm;
        }
    } else {
        bf16x8 zb = {0, 0, 0, 0, 0, 0, 0, 0};
        *(bf16x8*)&nbr_s[(wave * 16 + r16) * 72 + q * 8]      = zb;
        *(bf16x8*)&nbr_s[(wave * 16 + r16) * 72 + 32 + q * 8] = zb;
        if (q == 0) { s_s[wave * 16 + r16] = NEGf; com_s[wave * 16 + r16] = 0.f; }
    }
    __syncthreads();

    // ---- softmax over j (per pixel r16; broadcast reads) ----
    float sj[4], cj[4];
    #pragma unroll
    for (int j = 0; j < 4; ++j) { sj[j] = s_s[j * 16 + r16]; cj[j] = com_s[j * 16 + r16]; }
    float m = fmaxf(fmaxf(sj[0], sj[1]), fmaxf(sj[2], sj[3]));
    float e[4], sum = 0.f;
    #pragma unroll
    for (int j = 0; j < 4; ++j) { e[j] = __expf(sj[j] - m); sum += e[j]; }
    float inv = 1.f / sum;
    float wgt[4];
    #pragma unroll
    for (int j = 0; j < 4; ++j) wgt[j] = e[j] * inv * cj[j];

    // ---- weighted nbr sum -> upd A-fragments ----
    float uf0[8], uf1[8];
    #pragma unroll
    for (int i = 0; i < 8; ++i) { uf0[i] = 0.f; uf1[i] = 0.f; }
    #pragma unroll
    for (int j = 0; j < 4; ++j) {
        float wj = wgt[j];
        bf16x8 n0 = *(const bf16x8*)&nbr_s[(j * 16 + r16) * 72 + q * 8];
        bf16x8 n1 = *(const bf16x8*)&nbr_s[(j * 16 + r16) * 72 + 32 + q * 8];
        #pragma unroll
        for (int i = 0; i < 8; ++i) {
            uf0[i] = fmaf(wj, b2f((unsigned short)n0[i]), uf0[i]);
            uf1[i] = fmaf(wj, b2f((unsigned short)n1[i]), uf1[i]);
        }
    }
    BU p0, p1;
    #pragma unroll
    for (int i = 0; i < 8; ++i) { p0.s[i] = f2bf(uf0[i]); p1.s[i] = f2bf(uf1[i]); }

    // ---- output MLP: each wave computes out channels wave*16..+15 ----
    f32x4 acc3 = z4;
    #pragma unroll
    for (int ks = 0; ks < 2; ++ks) {
        bf16x8 A = ks ? p1.v : p0.v;
        bf16x8 bw = *(const bf16x8*)(mwT + (size_t)(wave * 16 + r16) * 64 + ks * 32 + q * 8);
        acc3 = __builtin_amdgcn_mfma_f32_16x16x32_bf16(A, bw, acc3, 0, 0, 0);
    }
    __syncthreads();   // all nbr_s reads done; reuse region as outT

    float* outT = (float*)pool;        // [64 d][20]
    {
        int d = wave * 16 + r16;
        float mb = mlp_b[d];
        #pragma unroll
        for (int r = 0; r < 4; ++r)
            outT[d * 20 + q * 4 + r] = acc3[r] + mb;
    }
    __syncthreads();
    {
        int d = t >> 2, c4 = (t & 3) * 4;
        float4 v = *(const float4*)&outT[d * 20 + c4];
        *(float4*)&out[((size_t)(b * CC + d)) * HW + pix0 + c4] = v;
    }
}

// ---------------- launch ----------------

extern "C" void kernel_launch(void* const* d_in, const int* in_sizes, int n_in,
                              void* d_out, int out_size, void* d_ws, size_t ws_size,
                              hipStream_t stream)
{
    const float* x    = (const float*)d_in[0];
    const float* mask = (const float*)d_in[1];
    const int*   rec  = (const int*)  d_in[2];
    const float* ptm  = (const float*)d_in[3];
    const float* w1   = (const float*)d_in[4];
    const float* cb1  = (const float*)d_in[5];
    const float* g1   = (const float*)d_in[6];
    const float* be1  = (const float*)d_in[7];
    const float* rm1  = (const float*)d_in[8];
    const float* rv1  = (const float*)d_in[9];
    const float* w2   = (const float*)d_in[10];
    const float* cb2  = (const float*)d_in[11];
    const float* g2   = (const float*)d_in[12];
    const float* be2  = (const float*)d_in[13];
    const float* rm2  = (const float*)d_in[14];
    const float* rv2  = (const float*)d_in[15];
    const float* w3   = (const float*)d_in[16];
    const float* cb3  = (const float*)d_in[17];
    const float* g3   = (const float*)d_in[18];
    const float* be3  = (const float*)d_in[19];
    const float* rm3  = (const float*)d_in[20];
    const float* rv3  = (const float*)d_in[21];
    const float* w4   = (const float*)d_in[22];
    const float* cb4  = (const float*)d_in[23];
    const float* mlpw = (const float*)d_in[24];
    const float* mlpb = (const float*)d_in[25];
    float* out = (float*)d_out;

    unsigned short* w1T = (unsigned short*)d_ws;   // 16384
    unsigned short* w2T = w1T + 16384;             // 4096
    unsigned short* mwT = w2T + 4096;              // 4096
    float* kk1 = (float*)(mwT + 4096);
    float* bb1 = kk1 + 128;
    float* kk2 = bb1 + 128;
    float* bb2 = kk2 + 32;
    float* kk3 = bb2 + 32;
    float* bb3 = kk3 + 8;

    k_prep<<<dim3(97), dim3(256), 0, stream>>>(
        w1, w2, mlpw, cb1, g1, be1, rm1, rv1, cb2, g2, be2, rm2, rv2,
        cb3, g3, be3, rm3, rv3, w1T, w2T, mwT, kk1, bb1, kk2, bb2, kk3, bb3);

    k_fused<<<dim3(2400), dim3(256), 0, stream>>>(
        x, mask, rec, ptm, w1T, w2T, mwT,
        kk1, bb1, kk2, bb2, kk3, bb3,
        w3, w4, cb4, mlpb, out);
}

// Round 5
// 167.150 us; speedup vs baseline: 1.0869x; 1.0869x over previous
//
#include <hip/hip_runtime.h>
#include <math.h>

#define CC 64
#define HH 80
#define WW 160
#define BB 3
#define LL 4
#define HW (HH * WW)          // 12800
#define EPSf 1e-5f
#define NEGf -1e30f

typedef __attribute__((ext_vector_type(8))) short bf16x8;
typedef __attribute__((ext_vector_type(4))) float f32x4;

union BU { unsigned short s[8]; bf16x8 v; };

__device__ __forceinline__ unsigned short f2bf(float f) {
    unsigned int u = __float_as_uint(f);
    u = u + 0x7fffu + ((u >> 16) & 1u);      // RNE
    return (unsigned short)(u >> 16);
}
__device__ __forceinline__ float b2f(unsigned short h) {
    return __uint_as_float(((unsigned int)h) << 16);
}

__device__ __forceinline__ void src_xy(const float* __restrict__ th, int pix,
                                       float& px, float& py) {
    int w = pix % WW, h = pix / WW;
    float gx = -1.f + 2.f * (float)w / (float)(WW - 1);
    float gy = -1.f + 2.f * (float)h / (float)(HH - 1);
    float sx = th[0] * gx + th[1] * gy + th[2];
    float sy = th[3] * gx + th[4] * gy + th[5];
    px = (sx + 1.f) * (float)(WW - 1) * 0.5f;
    py = (sy + 1.f) * (float)(HH - 1) * 0.5f;
}

struct Tap { int a00, a01, a10, a11; float w00, w01, w10, w11; };

__device__ __forceinline__ Tap mk_tap(float px, float py) {
    Tap tp;
    float x0f = floorf(px), y0f = floorf(py);
    float wx = px - x0f, wy = py - y0f;
    int x0 = (int)x0f, y0 = (int)y0f, x1 = x0 + 1, y1 = y0 + 1;
    float bx0 = (x0 >= 0 && x0 < WW) ? 1.f : 0.f;
    float bx1 = (x1 >= 0 && x1 < WW) ? 1.f : 0.f;
    float by0 = (y0 >= 0 && y0 < HH) ? 1.f : 0.f;
    float by1 = (y1 >= 0 && y1 < HH) ? 1.f : 0.f;
    int xc0 = min(max(x0, 0), WW - 1), xc1 = min(max(x1, 0), WW - 1);
    int yc0 = min(max(y0, 0), HH - 1), yc1 = min(max(y1, 0), HH - 1);
    tp.w00 = (1.f - wx) * (1.f - wy) * bx0 * by0;
    tp.w01 = wx * (1.f - wy) * bx1 * by0;
    tp.w10 = (1.f - wx) * wy * bx0 * by1;
    tp.w11 = wx * wy * bx1 * by1;
    tp.a00 = yc0 * WW + xc0; tp.a01 = yc0 * WW + xc1;
    tp.a10 = yc1 * WW + xc0; tp.a11 = yc1 * WW + xc1;
    return tp;
}

// ---------------- prep: weight transpose+bf16, BN folding ----------------

__global__ __launch_bounds__(256) void k_prep(
    const float* __restrict__ w1, const float* __restrict__ w2,
    const float* __restrict__ mlpw,
    const float* __restrict__ cb1, const float* __restrict__ g1,
    const float* __restrict__ be1, const float* __restrict__ rm1, const float* __restrict__ rv1,
    const float* __restrict__ cb2, const float* __restrict__ g2,
    const float* __restrict__ be2, const float* __restrict__ rm2, const float* __restrict__ rv2,
    const float* __restrict__ cb3, const float* __restrict__ g3,
    const float* __restrict__ be3, const float* __restrict__ rm3, const float* __restrict__ rv3,
    unsigned short* __restrict__ w1T, unsigned short* __restrict__ w2T,
    unsigned short* __restrict__ mwT,
    float* __restrict__ kk1, float* __restrict__ bb1,
    float* __restrict__ kk2, float* __restrict__ bb2,
    float* __restrict__ kk3, float* __restrict__ bb3)
{
    int idx = blockIdx.x * 256 + threadIdx.x;
    if (idx < 16384) {                       // w1T[o][c] = w1[c][o]
        int o = idx >> 7, c = idx & 127;
        w1T[idx] = f2bf(w1[c * 128 + o]);
    } else if (idx < 20480) {                // w2T[o2][o] = w2[o][o2]
        int i = idx - 16384;
        int o2 = i >> 7, o = i & 127;
        w2T[i] = f2bf(w2[o * 32 + o2]);
    } else if (idx < 24576) {                // mwT[d][c] = mlpw[c][d]
        int i = idx - 20480;
        int d = i >> 6, c = i & 63;
        mwT[i] = f2bf(mlpw[c * 64 + d]);
    } else if (idx < 24704) {
        int o = idx - 24576;
        float k = g1[o] * rsqrtf(rv1[o] + EPSf);
        kk1[o] = k; bb1[o] = fmaf(cb1[o] - rm1[o], k, be1[o]);
    } else if (idx < 24736) {
        int o = idx - 24704;
        float k = g2[o] * rsqrtf(rv2[o] + EPSf);
        kk2[o] = k; bb2[o] = fmaf(cb2[o] - rm2[o], k, be2[o]);
    } else if (idx < 24744) {
        int o = idx - 24736;
        float k = g3[o] * rsqrtf(rv3[o] + EPSf);
        kk3[o] = k; bb3[o] = fmaf(cb3[o] - rm3[o], k, be3[o]);
    }
}

// ---------------- fused, pixel-major gather ----------------
// grid: 1200 blocks (XCD-swizzled) of 256 threads = 4 waves; 32-px tiles.
// Phase A: wave w gathers nbr j=w pixel-major -> LDS [px][ch]; ego staged by all.
// Phase B: wave w runs layers 1-4 for j=w (MFMA, A-frags from LDS b128).
// Fuse: wave w = (mt, nh) does softmax + weighted sum + out-MLP MFMA.

__global__ __launch_bounds__(256, 3) void k_fused(
    const float* __restrict__ x, const float* __restrict__ mask,
    const int* __restrict__ rec, const float* __restrict__ ptm,
    const unsigned short* __restrict__ w1T, const unsigned short* __restrict__ w2T,
    const unsigned short* __restrict__ mwT,
    const float* __restrict__ kk1, const float* __restrict__ bb1,
    const float* __restrict__ kk2, const float* __restrict__ bb2,
    const float* __restrict__ kk3, const float* __restrict__ bb3,
    const float* __restrict__ w3, const float* __restrict__ w4,
    const float* __restrict__ cb4, const float* __restrict__ mlp_b,
    float* __restrict__ out)
{
    __shared__ __align__(16) char pool[50688];
    unsigned short* nbr_s = (unsigned short*)pool;            // [4j][32px][72] bf16 (18432 B)
    unsigned short* ego_s = (unsigned short*)(pool + 18432);  // [32px][72] bf16   (4608 B)
    unsigned short* H1s   = (unsigned short*)(pool + 23040);  // [4w][16px][136]   (17408 B)
    float* H2s   = (float*)(pool + 40448);                    // [4w][16px][36]    (9216 B)
    float* s_s   = (float*)(pool + 49664);                    // [4j][32px]        (512 B)
    float* com_s = (float*)(pool + 50176);                    // [4j][32px]        (512 B)

    int t = threadIdx.x;
    int bid = blockIdx.x;
    int work = (bid & 7) * 150 + (bid >> 3);   // XCD-contiguous slices
    int b = work / 400, tile = work % 400;
    int pix0 = tile * 32;

    int wave = t >> 6, lane = t & 63, q = lane >> 4, r16 = lane & 15;

    int r0 = rec[0], r1 = rec[1], r2 = rec[2];
    int rb = (b == 0) ? r0 : ((b == 1) ? r1 : r2);
    int off = (b >= 1 ? r0 : 0) + (b >= 2 ? r1 : 0);
    bool validw = (wave < rb);

    // ================= Phase A: staging =================
    {
        int pxA = lane & 31, cb = lane >> 5;     // lane = pixel, channel half
        int pix = pix0 + pxA;
        if (validw) {
            const float* th = ptm + (size_t)(b * 4 + wave) * 24;  // ptm[b][wave][0]
            float fx, fy; src_xy(th, pix, fx, fy);
            Tap tp = mk_tap(fx, fy);
            if (cb == 0) {
                const float* mk = mask + (size_t)(b * 4 + wave) * HW;
                float wm = tp.w00 * mk[tp.a00] + tp.w01 * mk[tp.a01]
                         + tp.w10 * mk[tp.a10] + tp.w11 * mk[tp.a11];
                com_s[wave * 32 + pxA] = wm;
            }
            const float* feat = x + (size_t)(off + wave) * CC * HW;
            unsigned short* dst = nbr_s + (size_t)(wave * 32 + pxA) * 72;
            #pragma unroll
            for (int i8 = 0; i8 < 4; ++i8) {
                BU pk;
                #pragma unroll
                for (int i = 0; i < 8; ++i) {
                    const float* f = feat + (size_t)(cb * 32 + i8 * 8 + i) * HW;
                    pk.s[i] = f2bf(tp.w00 * f[tp.a00] + tp.w01 * f[tp.a01]
                                 + tp.w10 * f[tp.a10] + tp.w11 * f[tp.a11]);
                }
                *(bf16x8*)(dst + cb * 32 + i8 * 8) = pk.v;
            }
        } else {
            bf16x8 zb = {0,0,0,0,0,0,0,0};
            unsigned short* dst = nbr_s + (size_t)(wave * 32 + pxA) * 72;
            #pragma unroll
            for (int i8 = 0; i8 < 4; ++i8)
                *(bf16x8*)(dst + cb * 32 + i8 * 8) = zb;
            if (cb == 0) { s_s[wave * 32 + pxA] = NEGf; com_s[wave * 32 + pxA] = 0.f; }
        }
        // ego staging: all 256 threads; channels cb8*8..+7, pixel t&31
        int pxe = t & 31, cb8 = t >> 5;
        const float* xe = x + (size_t)off * CC * HW + pix0 + pxe;
        BU pk;
        #pragma unroll
        for (int i = 0; i < 8; ++i)
            pk.s[i] = f2bf(xe[(size_t)(cb8 * 8 + i) * HW]);
        *(bf16x8*)(ego_s + (size_t)pxe * 72 + cb8 * 8) = pk.v;
    }
    __syncthreads();

    // ================= Phase B: MLP for j = wave =================
    const f32x4 z4 = {0.f, 0.f, 0.f, 0.f};
    if (validw) {
        unsigned short* H1w = H1s + wave * (16 * 136);
        float* H2w = H2s + wave * (16 * 36);

        // --- layer 1: K=128 -> N=128, M=32 (2 m-tiles), B reused across mt ---
        f32x4 acc[2][8];
        #pragma unroll
        for (int mt = 0; mt < 2; ++mt)
            #pragma unroll
            for (int nt = 0; nt < 8; ++nt) acc[mt][nt] = z4;

        #pragma unroll
        for (int ks = 0; ks < 4; ++ks) {
            int kcol = (ks & 1) * 32 + q * 8;    // ks 0,1: nbr ch; 2,3: ego ch
            const unsigned short* base = (ks < 2)
                ? (nbr_s + (size_t)(wave * 32) * 72) : ego_s;
            bf16x8 A0 = *(const bf16x8*)(base + (size_t)r16 * 72 + kcol);
            bf16x8 A1 = *(const bf16x8*)(base + (size_t)(16 + r16) * 72 + kcol);
            #pragma unroll
            for (int nt = 0; nt < 8; ++nt) {
                bf16x8 bw = *(const bf16x8*)(w1T + (size_t)(nt * 16 + r16) * 128
                                             + ks * 32 + q * 8);
                acc[0][nt] = __builtin_amdgcn_mfma_f32_16x16x32_bf16(A0, bw, acc[0][nt], 0, 0, 0);
                acc[1][nt] = __builtin_amdgcn_mfma_f32_16x16x32_bf16(A1, bw, acc[1][nt], 0, 0, 0);
            }
        }

        #pragma unroll
        for (int mt = 0; mt < 2; ++mt) {
            // BN1 + relu -> H1w (16 rows, reused per mt)
            #pragma unroll
            for (int nt = 0; nt < 8; ++nt) {
                int o = nt * 16 + r16;
                float kv = kk1[o], bv = bb1[o];
                #pragma unroll
                for (int r = 0; r < 4; ++r) {
                    float h = fmaxf(fmaf(acc[mt][nt][r], kv, bv), 0.f);
                    H1w[(q * 4 + r) * 136 + o] = f2bf(h);
                }
            }
            // --- layer 2: 128 -> 32 ---
            f32x4 acc2[2]; acc2[0] = z4; acc2[1] = z4;
            #pragma unroll
            for (int ks = 0; ks < 4; ++ks) {
                int kcol = ks * 32 + q * 8;
                bf16x8 A = *(const bf16x8*)&H1w[r16 * 136 + kcol];
                #pragma unroll
                for (int nt = 0; nt < 2; ++nt) {
                    bf16x8 bw = *(const bf16x8*)(w2T + (size_t)(nt * 16 + r16) * 128 + kcol);
                    acc2[nt] = __builtin_amdgcn_mfma_f32_16x16x32_bf16(A, bw, acc2[nt], 0, 0, 0);
                }
            }
            #pragma unroll
            for (int nt = 0; nt < 2; ++nt) {
                int o = nt * 16 + r16;
                float kv = kk2[o], bv = bb2[o];
                #pragma unroll
                for (int r = 0; r < 4; ++r) {
                    float h = fmaxf(fmaf(acc2[nt][r], kv, bv), 0.f);
                    H2w[(q * 4 + r) * 36 + o] = h;
                }
            }
            // --- layers 3-4 (q==0 lanes; pixel = mt*16 + r16) ---
            if (q == 0) {
                float a3[8];
                #pragma unroll
                for (int o = 0; o < 8; ++o) a3[o] = 0.f;
                #pragma unroll 4
                for (int c = 0; c < 32; ++c) {
                    float hv = H2w[r16 * 36 + c];
                    #pragma unroll
                    for (int o = 0; o < 8; ++o) a3[o] = fmaf(hv, w3[c * 8 + o], a3[o]);
                }
                float s = cb4[0];
                #pragma unroll
                for (int o = 0; o < 8; ++o) {
                    float h = fmaxf(fmaf(a3[o], kk3[o], bb3[o]), 0.f);
                    s = fmaf(h, w4[o], s);
                }
                s = fmaxf(s, 0.f);
                int pxs = mt * 16 + r16;
                float wm = com_s[wave * 32 + pxs];
                s_s[wave * 32 + pxs] = (wm == 0.f) ? NEGf : s;
            }
        }
    }
    __syncthreads();

    // ================= Fuse: wave = (mt, nh) =================
    int mt = wave & 1, nh = wave >> 1;
    int px = mt * 16 + r16;

    float sj[4], cj[4];
    #pragma unroll
    for (int j = 0; j < 4; ++j) { sj[j] = s_s[j * 32 + px]; cj[j] = com_s[j * 32 + px]; }
    float m = fmaxf(fmaxf(sj[0], sj[1]), fmaxf(sj[2], sj[3]));
    float e[4], sum = 0.f;
    #pragma unroll
    for (int j = 0; j < 4; ++j) { e[j] = __expf(sj[j] - m); sum += e[j]; }
    float inv = 1.f / sum;
    float wgt[4];
    #pragma unroll
    for (int j = 0; j < 4; ++j) wgt[j] = e[j] * inv * cj[j];

    float uf0[8], uf1[8];
    #pragma unroll
    for (int i = 0; i < 8; ++i) { uf0[i] = 0.f; uf1[i] = 0.f; }
    #pragma unroll
    for (int j = 0; j < 4; ++j) {
        float wj = wgt[j];
        bf16x8 n0 = *(const bf16x8*)&nbr_s[(size_t)(j * 32 + px) * 72 + q * 8];
        bf16x8 n1 = *(const bf16x8*)&nbr_s[(size_t)(j * 32 + px) * 72 + 32 + q * 8];
        #pragma unroll
        for (int i = 0; i < 8; ++i) {
            uf0[i] = fmaf(wj, b2f((unsigned short)n0[i]), uf0[i]);
            uf1[i] = fmaf(wj, b2f((unsigned short)n1[i]), uf1[i]);
        }
    }
    BU p0, p1;
    #pragma unroll
    for (int i = 0; i < 8; ++i) { p0.s[i] = f2bf(uf0[i]); p1.s[i] = f2bf(uf1[i]); }

    // out-MLP: this wave covers out channels nh*32..+31 for pixels mt*16..+15
    f32x4 acc3[2]; acc3[0] = z4; acc3[1] = z4;
    #pragma unroll
    for (int ks = 0; ks < 2; ++ks) {
        bf16x8 A = ks ? p1.v : p0.v;
        #pragma unroll
        for (int nt = 0; nt < 2; ++nt) {
            bf16x8 bw = *(const bf16x8*)(mwT + (size_t)(nh * 32 + nt * 16 + r16) * 64
                                         + ks * 32 + q * 8);
            acc3[nt] = __builtin_amdgcn_mfma_f32_16x16x32_bf16(A, bw, acc3[nt], 0, 0, 0);
        }
    }
    __syncthreads();   // all nbr_s reads done; overlay outT on pool start

    float* outT = (float*)pool;        // [64 d][36]
    #pragma unroll
    for (int nt = 0; nt < 2; ++nt) {
        int d = nh * 32 + nt * 16 + r16;
        float mb = mlp_b[d];
        #pragma unroll
        for (int r = 0; r < 4; ++r)
            outT[d * 36 + mt * 16 + q * 4 + r] = acc3[nt][r] + mb;
    }
    __syncthreads();
    {
        int d = t >> 2, c8 = (t & 3) * 8;
        float4 v0 = *(const float4*)&outT[d * 36 + c8];
        float4 v1 = *(const float4*)&outT[d * 36 + c8 + 4];
        float* op = out + ((size_t)(b * CC + d)) * HW + pix0 + c8;
        *(float4*)op = v0;
        *(float4*)(op + 4) = v1;
    }
}

// ---------------- launch ----------------

extern "C" void kernel_launch(void* const* d_in, const int* in_sizes, int n_in,
                              void* d_out, int out_size, void* d_ws, size_t ws_size,
                              hipStream_t stream)
{
    const float* x    = (const float*)d_in[0];
    const float* mask = (const float*)d_in[1];
    const int*   rec  = (const int*)  d_in[2];
    const float* ptm  = (const float*)d_in[3];
    const float* w1   = (const float*)d_in[4];
    const float* cb1  = (const float*)d_in[5];
    const float* g1   = (const float*)d_in[6];
    const float* be1  = (const float*)d_in[7];
    const float* rm1  = (const float*)d_in[8];
    const float* rv1  = (const float*)d_in[9];
    const float* w2   = (const float*)d_in[10];
    const float* cb2  = (const float*)d_in[11];
    const float* g2   = (const float*)d_in[12];
    const float* be2  = (const float*)d_in[13];
    const float* rm2  = (const float*)d_in[14];
    const float* rv2  = (const float*)d_in[15];
    const float* w3   = (const float*)d_in[16];
    const float* cb3  = (const float*)d_in[17];
    const float* g3   = (const float*)d_in[18];
    const float* be3  = (const float*)d_in[19];
    const float* rm3  = (const float*)d_in[20];
    const float* rv3  = (const float*)d_in[21];
    const float* w4   = (const float*)d_in[22];
    const float* cb4  = (const float*)d_in[23];
    const float* mlpw = (const float*)d_in[24];
    const float* mlpb = (const float*)d_in[25];
    float* out = (float*)d_out;

    unsigned short* w1T = (unsigned short*)d_ws;   // 16384
    unsigned short* w2T = w1T + 16384;             // 4096
    unsigned short* mwT = w2T + 4096;              // 4096
    float* kk1 = (float*)(mwT + 4096);
    float* bb1 = kk1 + 128;
    float* kk2 = bb1 + 128;
    float* bb2 = kk2 + 32;
    float* kk3 = bb2 + 32;
    float* bb3 = kk3 + 8;

    k_prep<<<dim3(97), dim3(256), 0, stream>>>(
        w1, w2, mlpw, cb1, g1, be1, rm1, rv1, cb2, g2, be2, rm2, rv2,
        cb3, g3, be3, rm3, rv3, w1T, w2T, mwT, kk1, bb1, kk2, bb2, kk3, bb3);

    k_fused<<<dim3(1200), dim3(256), 0, stream>>>(
        x, mask, rec, ptm, w1T, w2T, mwT,
        kk1, bb1, kk2, bb2, kk3, bb3,
        w3, w4, cb4, mlpb, out);
}